// Round 11
// baseline (270.635 us; speedup 1.0000x reference)
//
#include <hip/hip_runtime.h>
#include <stdint.h>

#define B_ 2
#define S_ 2048
#define H_ 1024
#define NH_ 16
#define DK_ 64
#define M_ (B_*S_)

typedef __attribute__((ext_vector_type(8))) short short8;
typedef __attribute__((ext_vector_type(4))) float f32x4;
typedef __attribute__((ext_vector_type(16))) float f32x16;
typedef __attribute__((ext_vector_type(4))) unsigned u32x4;

#define GLDS16(g, s) __builtin_amdgcn_global_load_lds( \
    (const __attribute__((address_space(1))) unsigned int*)(g), \
    (__attribute__((address_space(3))) unsigned int*)(s), 16, 0, 0)

__device__ __forceinline__ unsigned short f2bf(float x) {
  union { float f; unsigned u; } c; c.f = x;
  unsigned r = (c.u + 0x7FFF + ((c.u >> 16) & 1)) >> 16;
  return (unsigned short)r;
}

// ---------------- fp32 -> bf16 converts ----------------
__global__ void k_cvt3(const float4* __restrict__ a, const float4* __restrict__ b,
                       const float4* __restrict__ c,
                       ushort4* __restrict__ oa, ushort4* __restrict__ ob,
                       ushort4* __restrict__ oc) {
  int idx = blockIdx.x * 256 + threadIdx.x;      // 3 * 2^20
  int t = idx >> 20, i = idx & ((1 << 20) - 1);
  const float4* s = (t == 0) ? a : (t == 1) ? b : c;
  ushort4* o = (t == 0) ? oa : (t == 1) ? ob : oc;
  float4 v = s[i];
  ushort4 r; r.x = f2bf(v.x); r.y = f2bf(v.y); r.z = f2bf(v.z); r.w = f2bf(v.w);
  o[i] = r;
}

__global__ void k_cvtw(const float4* __restrict__ a, const float4* __restrict__ b,
                       const float4* __restrict__ c, const float4* __restrict__ d,
                       ushort4* __restrict__ oa, ushort4* __restrict__ ob,
                       ushort4* __restrict__ oc, ushort4* __restrict__ od) {
  int idx = blockIdx.x * 256 + threadIdx.x;      // 4 * 2^18
  int t = idx >> 18, i = idx & ((1 << 18) - 1);
  const float4* s = (t == 0) ? a : (t == 1) ? b : (t == 2) ? c : d;
  ushort4* o = (t == 0) ? oa : (t == 1) ? ob : (t == 2) ? oc : od;
  float4 v = s[i];
  ushort4 r; r.x = f2bf(v.x); r.y = f2bf(v.y); r.z = f2bf(v.z); r.w = f2bf(v.w);
  o[i] = r;
}

// ---------------- GEMM: C = A(MxK) * Bw(NxK)^T + bias, K=1024 ----------------
// 2-phase double-buffered staging: STAGE(k+1) issued BEFORE compute(k); one
// barrier per K-step (its vmcnt drain lands after ~1100cy of MFMA, not before).
enum { MODE_Q = 0, MODE_K = 1, MODE_VT = 2, MODE_F32 = 3 };

__device__ __forceinline__ void gemm_body(
    const unsigned short* __restrict__ A, const unsigned short* __restrict__ Bw,
    const float* __restrict__ bias, const int* __restrict__ amask,
    void* __restrict__ Cout, int mode, int bx, int by) {
  __shared__ unsigned short As[2][128 * 64];   // [buf][row][64], swizzled chunks
  __shared__ unsigned short Bs[2][128 * 64];
  const int tid = threadIdx.x;
  const int w = tid >> 6, lane = tid & 63;
  const int lr = lane & 15, hi = lane >> 4;
  const int wr = w >> 1, wc = w & 1;
  const int m0 = by * 128, n0 = bx * 128;

  // per-thread staging sources (advance by k0)
  const unsigned short* asrc[4];
  const unsigned short* bsrc[4];
#pragma unroll
  for (int it = 0; it < 4; ++it) {
    int c = it * 256 + tid;
    int row = c >> 3, ch = c & 7;
    asrc[it] = A + (size_t)(m0 + row) * H_ + ((ch ^ (row & 7)) << 3);
    bsrc[it] = Bw + (size_t)(n0 + row) * H_ + ((ch ^ (row & 7)) << 3);
  }

  f32x4 acc[4][4];
#pragma unroll
  for (int i = 0; i < 4; i++)
#pragma unroll
    for (int j = 0; j < 4; j++) acc[i][j] = (f32x4){0.f, 0.f, 0.f, 0.f};

  // prologue: stage k0=0 into buf 0
#pragma unroll
  for (int it = 0; it < 4; ++it) {
    GLDS16(asrc[it], &As[0][(it * 256 + w * 64) * 8]);
    GLDS16(bsrc[it], &Bs[0][(it * 256 + w * 64) * 8]);
  }
  __syncthreads();

  for (int k0 = 0; k0 < H_; k0 += 64) {
    const int cur = (k0 >> 6) & 1;
    if (k0 + 64 < H_) {   // issue next K-tile's staging EARLY (2-phase)
#pragma unroll
      for (int it = 0; it < 4; ++it) {
        GLDS16(asrc[it] + k0 + 64, &As[cur ^ 1][(it * 256 + w * 64) * 8]);
        GLDS16(bsrc[it] + k0 + 64, &Bs[cur ^ 1][(it * 256 + w * 64) * 8]);
      }
    }
#pragma unroll
    for (int ks = 0; ks < 2; ++ks) {
      short8 af[4], bfg[4];
#pragma unroll
      for (int mi = 0; mi < 4; ++mi) {
        int row = wr * 64 + mi * 16 + lr;
        int ch = ((ks << 2) | hi) ^ (lr & 7);
        af[mi] = *(const short8*)((const char*)As[cur] + row * 128 + (ch << 4));
      }
#pragma unroll
      for (int ni = 0; ni < 4; ++ni) {
        int row = wc * 64 + ni * 16 + lr;
        int ch = ((ks << 2) | hi) ^ (lr & 7);
        bfg[ni] = *(const short8*)((const char*)Bs[cur] + row * 128 + (ch << 4));
      }
#pragma unroll
      for (int mi = 0; mi < 4; ++mi)
#pragma unroll
        for (int ni = 0; ni < 4; ++ni)
          acc[mi][ni] = __builtin_amdgcn_mfma_f32_16x16x32_bf16(af[mi], bfg[ni], acc[mi][ni], 0, 0, 0);
    }
    __syncthreads();   // drains staging of k0+64 + this tile's LDS reads
  }

  float bvv[4];
#pragma unroll
  for (int ni = 0; ni < 4; ++ni) bvv[ni] = bias[n0 + wc * 64 + ni * 16 + lr];

  if (mode == MODE_Q || mode == MODE_K) {
    unsigned short* C = (unsigned short*)Cout;
    float km[4][4];
    if (mode == MODE_K) {
#pragma unroll
      for (int mi = 0; mi < 4; ++mi)
#pragma unroll
        for (int j = 0; j < 4; ++j) {
          int r = m0 + wr * 64 + mi * 16 + hi * 4 + j;
          km[mi][j] = amask[r] ? 1.0f : 0.0f;
        }
    }
#pragma unroll
    for (int mi = 0; mi < 4; ++mi)
#pragma unroll
      for (int ni = 0; ni < 4; ++ni) {
        int col = n0 + wc * 64 + ni * 16 + lr;
#pragma unroll
        for (int j = 0; j < 4; ++j) {
          int r = m0 + wr * 64 + mi * 16 + hi * 4 + j;
          float v = acc[mi][ni][j] + bvv[ni];
          // MODE_Q: fold 1/sqrt(DK) AND log2(e) so attention uses native exp2
          v *= (mode == MODE_Q) ? 0.180336879f : km[mi][j];
          C[(size_t)r * H_ + col] = f2bf(v);
        }
      }
  } else if (mode == MODE_F32) {
    float* C = (float*)Cout;
#pragma unroll
    for (int mi = 0; mi < 4; ++mi)
#pragma unroll
      for (int ni = 0; ni < 4; ++ni) {
        int col = n0 + wc * 64 + ni * 16 + lr;
#pragma unroll
        for (int j = 0; j < 4; ++j) {
          int r = m0 + wr * 64 + mi * 16 + hi * 4 + j;
          C[(size_t)r * H_ + col] = acc[mi][ni][j] + bvv[ni];
        }
      }
  } else {  // MODE_VT: Vt[(b*H + col)][s] = v, packed 4 bf16 along s
    unsigned short* Vt = (unsigned short*)Cout;
#pragma unroll
    for (int mi = 0; mi < 4; ++mi) {
      int rbase = m0 + wr * 64 + mi * 16 + hi * 4;
      int bb = rbase >> 11, s0 = rbase & (S_ - 1);
#pragma unroll
      for (int ni = 0; ni < 4; ++ni) {
        int col = n0 + wc * 64 + ni * 16 + lr;
        ushort4 pk;
        pk.x = f2bf(acc[mi][ni][0] + bvv[ni]);
        pk.y = f2bf(acc[mi][ni][1] + bvv[ni]);
        pk.z = f2bf(acc[mi][ni][2] + bvv[ni]);
        pk.w = f2bf(acc[mi][ni][3] + bvv[ni]);
        *(ushort4*)(Vt + (size_t)(bb * H_ + col) * S_ + s0) = pk;
      }
    }
  }
}

__global__ __launch_bounds__(256, 2) void k_gemm_qkv(
    const unsigned short* __restrict__ Xq, const unsigned short* __restrict__ Xk,
    const unsigned short* __restrict__ Xv,
    const unsigned short* __restrict__ Wqb, const unsigned short* __restrict__ Wkb,
    const unsigned short* __restrict__ Wvb,
    const float* __restrict__ bq, const float* __restrict__ bk,
    const float* __restrict__ bv, const int* __restrict__ amask,
    unsigned short* __restrict__ Qb, unsigned short* __restrict__ Kb,
    unsigned short* __restrict__ Vtb) {
  int z = blockIdx.z;
  const unsigned short* A = (z == 0) ? Xq : (z == 1) ? Xk : Xv;
  const unsigned short* W = (z == 0) ? Wqb : (z == 1) ? Wkb : Wvb;
  const float* bias = (z == 0) ? bq : (z == 1) ? bk : bv;
  void* C = (z == 0) ? (void*)Qb : (z == 1) ? (void*)Kb : (void*)Vtb;
  int mode = (z == 0) ? MODE_Q : (z == 1) ? MODE_K : MODE_VT;
  gemm_body(A, W, bias, amask, C, mode, blockIdx.x, blockIdx.y);
}

__global__ __launch_bounds__(256, 2) void k_gemm_o(
    const unsigned short* __restrict__ Ctx, const unsigned short* __restrict__ Wob,
    const float* __restrict__ bo, float* __restrict__ out) {
  gemm_body(Ctx, Wob, bo, nullptr, (void*)out, MODE_F32, blockIdx.x, blockIdx.y);
}

// ---------------- flash attention, 32x32x16 MFMA, 2-phase dbuf ----------------
// grid 1024 blocks x 128 thr: (b, h, qtile of 64). 2 waves x 32 q-rows. KVBLK=64.
// Scores arrive in log2 units (Q pre-scaled by 0.125*log2e); masked K rows zeroed.
// perm5 key staging (swap bits 2<->3 within 32-key block) makes the PV P-fragment
// lane-local (see r5 notes). 2-phase: STAGE(t+1) issued BEFORE compute(t); single
// barrier/iter -> staging latency hides under QK^T+softmax+PV. Defer-max (THR=8
// log2 units): rescale pass only when a lane's max grows.
__global__ __launch_bounds__(128, 2) void k_attn(
    const unsigned short* __restrict__ Qb, const unsigned short* __restrict__ Kb,
    const unsigned short* __restrict__ Vtb, unsigned short* __restrict__ Ctx) {
  __shared__ unsigned short Klds[2][64 * 64];   // [buf][row][dk], perm5'd rows
  __shared__ unsigned short Vtl[2][64 * 64];    // [buf][d][key]

  const int tid = threadIdx.x;
  const int w = tid >> 6, lane = tid & 63;
  const int l5 = lane & 31, hi5 = lane >> 5;
  int bid = (blockIdx.x & 7) * 128 + (blockIdx.x >> 3);  // XCD-chunked swizzle
  const int qt = bid & 31;
  const int h = (bid >> 5) & 15;
  const int b = bid >> 9;
  const int qr = qt * 64 + w * 32 + l5;   // this lane's q row (col of C)

  // Q fragment (B operand): col=q=l5, k = dkblk*16 + 8*hi5 + t
  short8 aq[4];
  {
    const unsigned short* qp = Qb + (size_t)(b * S_ + qr) * H_ + h * DK_ + hi5 * 8;
#pragma unroll
    for (int dkblk = 0; dkblk < 4; ++dkblk)
      aq[dkblk] = *(const short8*)(qp + dkblk * 16);
  }

  // staging source pointers (4 K chunks + 4 Vt chunks per thread per tile)
  const unsigned short* ksrc[4];
  const unsigned short* vsrc[4];
#pragma unroll
  for (int it = 0; it < 4; ++it) {
    int c = it * 128 + tid;            // 0..511 chunk id
    int rho = c >> 3, cl = c & 7;
    int kap = 32 * (rho >> 5) + ((rho & 19) | ((rho & 4) << 1) | ((rho & 8) >> 1));
    ksrc[it] = Kb + (size_t)(b * S_ + kap) * H_ + h * DK_ + ((cl ^ (rho & 7)) << 3);
    vsrc[it] = Vtb + (size_t)(b * H_ + h * DK_ + rho) * S_ + ((cl ^ (rho & 7)) << 3);
  }

  f32x16 ctx[2];
#pragma unroll
  for (int dblk = 0; dblk < 2; ++dblk)
#pragma unroll
    for (int i = 0; i < 16; ++i) ctx[dblk][i] = 0.f;
  float mrun = -30000.f, lrun = 0.f;

  // prologue: stage tile 0 into buf 0
#pragma unroll
  for (int it = 0; it < 4; ++it) {
    GLDS16(ksrc[it], &Klds[0][(it * 128 + w * 64) * 8]);
    GLDS16(vsrc[it], &Vtl[0][(it * 128 + w * 64) * 8]);
  }
  __syncthreads();

  for (int t = 0; t < S_ / 64; ++t) {
    const int cur = t & 1;
    if (t + 1 < S_ / 64) {     // issue next tile's staging EARLY (2-phase)
      int kv1 = (t + 1) * 64;
#pragma unroll
      for (int it = 0; it < 4; ++it) {
        GLDS16(ksrc[it] + (size_t)kv1 * H_, &Klds[cur ^ 1][(it * 128 + w * 64) * 8]);
        GLDS16(vsrc[it] + kv1, &Vtl[cur ^ 1][(it * 128 + w * 64) * 8]);
      }
    }

    // QK^T: sc[kb] over 32 keys x 32 q, A=K rows (perm5'd), B=Q
    f32x16 sc[2];
#pragma unroll
    for (int kb = 0; kb < 2; ++kb) {
      f32x16 a;
#pragma unroll
      for (int i = 0; i < 16; ++i) a[i] = 0.f;
#pragma unroll
      for (int dkblk = 0; dkblk < 4; ++dkblk) {
        int row = kb * 32 + l5;
        int ch = (2 * dkblk + hi5) ^ (row & 7);
        short8 kf = *(const short8*)((const char*)Klds[cur] + row * 128 + (ch << 4));
        a = __builtin_amdgcn_mfma_f32_32x32x16_bf16(kf, aq[dkblk], a, 0, 0, 0);
      }
      sc[kb] = a;
    }

    // online softmax in log2 units; defer-max rescale (THR=8)
    float mx = sc[0][0];
#pragma unroll
    for (int i = 1; i < 16; ++i) mx = fmaxf(mx, sc[0][i]);
#pragma unroll
    for (int i = 0; i < 16; ++i) mx = fmaxf(mx, sc[1][i]);
    mx = fmaxf(mx, __shfl_xor(mx, 32));
    if (!__all(mx <= mrun + 8.f)) {
      float mnew = fmaxf(mrun, mx);
      float scale = exp2f(mrun - mnew);
      mrun = mnew;
      lrun *= scale;
#pragma unroll
      for (int dblk = 0; dblk < 2; ++dblk)
#pragma unroll
        for (int i = 0; i < 16; ++i) ctx[dblk][i] *= scale;
    }
    float ps = 0.f;
#pragma unroll
    for (int kb = 0; kb < 2; ++kb)
#pragma unroll
      for (int i = 0; i < 16; ++i) {
        float e = exp2f(sc[kb][i] - mrun);
        sc[kb][i] = e;
        ps += e;
      }
    ps += __shfl_xor(ps, 32);
    lrun += ps;

    // PV: ctx^T += Vt * P^T ; P^T fragment lane-local (keys 16u+8*hi5+t)
#pragma unroll
    for (int kb = 0; kb < 2; ++kb)
#pragma unroll
      for (int u = 0; u < 2; ++u) {
        unsigned w0, w1, w2, w3;
        asm("v_cvt_pk_bf16_f32 %0, %1, %2" : "=v"(w0) : "v"(sc[kb][8*u+0]), "v"(sc[kb][8*u+1]));
        asm("v_cvt_pk_bf16_f32 %0, %1, %2" : "=v"(w1) : "v"(sc[kb][8*u+2]), "v"(sc[kb][8*u+3]));
        asm("v_cvt_pk_bf16_f32 %0, %1, %2" : "=v"(w2) : "v"(sc[kb][8*u+4]), "v"(sc[kb][8*u+5]));
        asm("v_cvt_pk_bf16_f32 %0, %1, %2" : "=v"(w3) : "v"(sc[kb][8*u+6]), "v"(sc[kb][8*u+7]));
        u32x4 wp; wp.x = w0; wp.y = w1; wp.z = w2; wp.w = w3;
        short8 pb = __builtin_bit_cast(short8, wp);
#pragma unroll
        for (int dblk = 0; dblk < 2; ++dblk) {
          int row = dblk * 32 + l5;
          int ch = (4 * kb + 2 * u + hi5) ^ (row & 7);
          short8 vt = *(const short8*)((const char*)Vtl[cur] + row * 128 + (ch << 4));
          ctx[dblk] = __builtin_amdgcn_mfma_f32_32x32x16_bf16(vt, pb, ctx[dblk], 0, 0, 0);
        }
      }

    __syncthreads();   // drains this iter's staging (vmcnt) + LDS reads
  }

  float inv = 1.0f / lrun;
  unsigned short* cp = Ctx + (size_t)(b * S_ + qr) * H_ + h * DK_;
#pragma unroll
  for (int dblk = 0; dblk < 2; ++dblk)
#pragma unroll
    for (int s = 0; s < 4; ++s) {
      ushort4 o;
      o.x = f2bf(ctx[dblk][4*s+0] * inv);
      o.y = f2bf(ctx[dblk][4*s+1] * inv);
      o.z = f2bf(ctx[dblk][4*s+2] * inv);
      o.w = f2bf(ctx[dblk][4*s+3] * inv);
      *(ushort4*)(cp + dblk * 32 + 8 * s + 4 * hi5) = o;
    }
}

// ---------------- launch ----------------
extern "C" void kernel_launch(void* const* d_in, const int* in_sizes, int n_in,
                              void* d_out, int out_size, void* d_ws, size_t ws_size,
                              hipStream_t stream) {
  (void)in_sizes; (void)n_in; (void)out_size; (void)ws_size;
  const float* query = (const float*)d_in[0];
  const float* key   = (const float*)d_in[1];
  const float* value = (const float*)d_in[2];
  const int*   amask = (const int*)d_in[3];
  const float* Wq = (const float*)d_in[4];
  const float* bq = (const float*)d_in[5];
  const float* Wk = (const float*)d_in[6];
  const float* bk = (const float*)d_in[7];
  const float* Wv = (const float*)d_in[8];
  const float* bv = (const float*)d_in[9];
  const float* Wo = (const float*)d_in[10];
  const float* bo = (const float*)d_in[11];
  float* out = (float*)d_out;

  unsigned short* ws = (unsigned short*)d_ws;
  const size_t SZX = (size_t)M_ * H_;       // 4194304
  const size_t SZW = (size_t)H_ * H_;       // 1048576
  unsigned short* Xq  = ws;
  unsigned short* Xk  = Xq + SZX;
  unsigned short* Xv  = Xk + SZX;
  unsigned short* Wqb = Xv + SZX;
  unsigned short* Wkb = Wqb + SZW;
  unsigned short* Wvb = Wkb + SZW;
  unsigned short* Wob = Wvb + SZW;
  unsigned short* Qb  = Wob + SZW;
  unsigned short* Kb  = Qb + SZX;
  unsigned short* Vtb = Kb + SZX;
  unsigned short* Ctx = Vtb + SZX;

  k_cvt3<<<dim3(12288), dim3(256), 0, stream>>>(
      (const float4*)query, (const float4*)key, (const float4*)value,
      (ushort4*)Xq, (ushort4*)Xk, (ushort4*)Xv);
  k_cvtw<<<dim3(4096), dim3(256), 0, stream>>>(
      (const float4*)Wq, (const float4*)Wk, (const float4*)Wv, (const float4*)Wo,
      (ushort4*)Wqb, (ushort4*)Wkb, (ushort4*)Wvb, (ushort4*)Wob);
  k_gemm_qkv<<<dim3(8, 32, 3), dim3(256), 0, stream>>>(
      Xq, Xk, Xv, Wqb, Wkb, Wvb, bq, bk, bv, amask, Qb, Kb, Vtb);
  k_attn<<<dim3(1024), dim3(128), 0, stream>>>(Qb, Kb, Vtb, Ctx);
  k_gemm_o<<<dim3(8, 32), dim3(256), 0, stream>>>(Ctx, Wob, bo, out);
}